// Round 1
// 963.171 us; speedup vs baseline: 1.0270x; 1.0270x over previous
//
#include <hip/hip_runtime.h>
#include <stdint.h>

// Problem constants: B=65536, N=20, C=128, H=4, HD=32, OC=128
// Fused design: 4096 blocks x 256 threads; one block = 16 rows.
//   Phase 0: Q = X@Wq^T + bq  (waves split n-tiles), T_h = Q_h@Wk_h (wave=head) -> LDS
//   Phase A: attention per row (4 rows per wave, sequential), S overwrites T in LDS
//   Phase B: s@Wv^T -> @Wo^T -> SE -> residual gate -> out   (waves split heads/n-tiles)

typedef short short8 __attribute__((ext_vector_type(8)));
typedef float f32x4 __attribute__((ext_vector_type(4)));

#define TSL 520   // short-stride of T/S rows in LDS (breaks bank-phase alignment)

__device__ __forceinline__ short f2bf(float f) {
  uint32_t u = __float_as_uint(f);
  u += 0x7FFFu + ((u >> 16) & 1u);   // round-to-nearest-even
  return (short)(u >> 16);
}
__device__ __forceinline__ short8 pk8(float4 a, float4 b) {
  short8 r;
  r[0] = f2bf(a.x); r[1] = f2bf(a.y); r[2] = f2bf(a.z); r[3] = f2bf(a.w);
  r[4] = f2bf(b.x); r[5] = f2bf(b.y); r[6] = f2bf(b.z); r[7] = f2bf(b.w);
  return r;
}
// unpack 8 bf16 (as uint4) -> 8 fp32
__device__ __forceinline__ void unpack8(uint4 u, float* f) {
  f[0] = __uint_as_float(u.x << 16); f[1] = __uint_as_float(u.x & 0xFFFF0000u);
  f[2] = __uint_as_float(u.y << 16); f[3] = __uint_as_float(u.y & 0xFFFF0000u);
  f[4] = __uint_as_float(u.z << 16); f[5] = __uint_as_float(u.z & 0xFFFF0000u);
  f[6] = __uint_as_float(u.w << 16); f[7] = __uint_as_float(u.w & 0xFFFF0000u);
}

// ---------------------------------------------------------------------------
// K0: weight prep — bf16 casts, Wk transposed (wkt[c][d] = Wk[d][c]).
// ---------------------------------------------------------------------------
__global__ __launch_bounds__(256) void k_prep(
    const float* __restrict__ Wq, const float* __restrict__ Wk,
    const float* __restrict__ Wv, const float* __restrict__ Wo,
    const float* __restrict__ Ws1, const float* __restrict__ Ws2,
    short* __restrict__ wq, short* __restrict__ wkt, short* __restrict__ wv,
    short* __restrict__ wo, short* __restrict__ ws1, short* __restrict__ ws2)
{
  int idx = blockIdx.x * 256 + threadIdx.x;
  int stride = gridDim.x * 256;
  for (int i = idx; i < 16384; i += stride) {
    wq[i] = f2bf(Wq[i]);
    wv[i] = f2bf(Wv[i]);
    wo[i] = f2bf(Wo[i]);
    int c = i >> 7, d = i & 127;
    wkt[i] = f2bf(Wk[d * 128 + c]);       // wkt[c*128+d] = Wk[d][c]
  }
  for (int i = idx; i < 4096; i += stride) {
    ws1[i] = f2bf(Ws1[i]);
    ws2[i] = f2bf(Ws2[i]);
  }
}

// ---------------------------------------------------------------------------
// K1: fully fused per-16-row-block pipeline.
// LDS: U  : phase0 qtile (16x136) -> phaseA per-wave lnb (4 x 20x136) -> phaseB ov/u (16x136)
//      R0 : T tile (16xTSL) -> S tile (in-place, per-row) -> o1 (16x136)
//      gz : cross-wave partials for the residual-gate dot
// ---------------------------------------------------------------------------
__global__ __launch_bounds__(256) void k_fused(
    const float* __restrict__ x, const float* __restrict__ nb,
    const float* __restrict__ bq,
    const short* __restrict__ wq, const short* __restrict__ wkt,
    const short* __restrict__ wv, const short* __restrict__ wo,
    const short* __restrict__ ws1, const short* __restrict__ ws2,
    const float* __restrict__ bv, const float* __restrict__ bo,
    const float* __restrict__ wg, const float* __restrict__ bg,
    float* __restrict__ out)
{
  __shared__ short U[10880];        // 21760 B
  __shared__ short R0[16 * TSL];    // 16640 B
  __shared__ float gz[4][17];

  const int wid  = threadIdx.x >> 6;
  const int lane = threadIdx.x & 63;
  const int g    = lane & 15;
  const int q4   = lane >> 4;
  // XCD-bijective swizzle (4096 % 8 == 0): each XCD gets a contiguous stripe.
  const int bid  = ((blockIdx.x & 7) << 9) | (blockIdx.x >> 3);
  const int r0   = bid << 4;

  // ===== Phase 0a: Q = X @ Wq^T + bq -> qtile (U). Wave wid does nt = 2*wid, 2*wid+1.
  short8 af[4];
#pragma unroll
  for (int ks = 0; ks < 4; ++ks) {
    const float* p = x + (size_t)(r0 + g) * 128 + ks * 32 + q4 * 8;
    af[ks] = pk8(*(const float4*)p, *(const float4*)(p + 4));
  }
#pragma unroll
  for (int t2 = 0; t2 < 2; ++t2) {
    const int nt = wid * 2 + t2;
    f32x4 acc = {0.f, 0.f, 0.f, 0.f};
#pragma unroll
    for (int ks = 0; ks < 4; ++ks) {
      short8 bfr = *(const short8*)(wq + (nt * 16 + g) * 128 + ks * 32 + q4 * 8);
      acc = __builtin_amdgcn_mfma_f32_16x16x32_bf16(af[ks], bfr, acc, 0, 0, 0);
    }
    const float bias = bq[nt * 16 + g];
#pragma unroll
    for (int i = 0; i < 4; ++i)
      U[(q4 * 4 + i) * 136 + nt * 16 + g] = f2bf(acc[i] + bias);
  }
  __syncthreads();

  // ===== Phase 0b: T_h = Q_h @ Wk_h -> R0 (bf16). Wave wid = head h.
  {
    const int h = wid;
    short8 a = *(const short8*)(U + g * 136 + h * 32 + q4 * 8);
#pragma unroll
    for (int nt = 0; nt < 8; ++nt) {
      short8 bfr = *(const short8*)(wkt + (nt * 16 + g) * 128 + h * 32 + q4 * 8);
      f32x4 acc = {0.f, 0.f, 0.f, 0.f};
      acc = __builtin_amdgcn_mfma_f32_16x16x32_bf16(a, bfr, acc, 0, 0, 0);
#pragma unroll
      for (int i = 0; i < 4; ++i)
        R0[(q4 * 4 + i) * TSL + h * 128 + nt * 16 + g] = f2bf(acc[i]);
    }
  }
  __syncthreads();

  // ===== Phase A: attention. Wave wid owns rows wid*4 .. wid*4+3 (sequential).
  {
    short* L = U + wid * 2720;       // per-wave 20x136 bf16 neighbor tile (aliases qtile: dead)
    const int h = q4;                // head group = lane>>4
    const float CSC = 0.25505417705366035f;   // log2(e)/sqrt(32)

    // prefetch row 0 neighbors into registers
    float4 pf[10];
    {
      const float* src0 = nb + ((size_t)r0 + wid * 4) * 2560;
#pragma unroll
      for (int j = 0; j < 5; ++j) {
        const int n = j * 4 + h;
        const float* p = src0 + n * 128 + g * 8;
        pf[2 * j]     = *(const float4*)p;
        pf[2 * j + 1] = *(const float4*)(p + 4);
      }
    }

#pragma unroll 1
    for (int it = 0; it < 4; ++it) {
      const int bl = wid * 4 + it;
      // commit prefetched row to LDS as bf16
#pragma unroll
      for (int j = 0; j < 5; ++j) {
        const int n = j * 4 + h;
        *(short8*)(L + n * 136 + g * 8) = pk8(pf[2 * j], pf[2 * j + 1]);
      }
      // t for this head (bf16 from LDS T tile)
      float t[8];
      unpack8(*(const uint4*)(R0 + bl * TSL + h * 128 + g * 8), t);

      // pass 1: scores
      float sc[20];
#pragma unroll
      for (int n = 0; n < 20; ++n) {
        float c[8];
        unpack8(*(const uint4*)(L + n * 136 + g * 8), c);
        float p = t[0]*c[0] + t[1]*c[1] + t[2]*c[2] + t[3]*c[3]
                + t[4]*c[4] + t[5]*c[5] + t[6]*c[6] + t[7]*c[7];
        p += __shfl_xor(p, 1);
        p += __shfl_xor(p, 2);
        p += __shfl_xor(p, 4);
        p += __shfl_xor(p, 8);
        sc[n] = p;
      }

      // prefetch next row's neighbors; latency hides under softmax + pass 2
      if (it < 3) {
        const float* srcn = nb + ((size_t)r0 + bl + 1) * 2560;
#pragma unroll
        for (int j = 0; j < 5; ++j) {
          const int n = j * 4 + h;
          const float* p = srcn + n * 128 + g * 8;
          pf[2 * j]     = *(const float4*)p;
          pf[2 * j + 1] = *(const float4*)(p + 4);
        }
      }

      // softmax (1/sqrt(32) folded into exp2)
      float mx = sc[0];
#pragma unroll
      for (int n = 1; n < 20; ++n) mx = fmaxf(mx, sc[n]);
      float sum = 0.f;
#pragma unroll
      for (int n = 0; n < 20; ++n) { sc[n] = exp2f((sc[n] - mx) * CSC); sum += sc[n]; }
      const float inv = 1.f / sum;

      // pass 2: weighted sum
      float s[8] = {0, 0, 0, 0, 0, 0, 0, 0};
#pragma unroll
      for (int n = 0; n < 20; ++n) {
        float c[8];
        unpack8(*(const uint4*)(L + n * 136 + g * 8), c);
#pragma unroll
        for (int k2 = 0; k2 < 8; ++k2) s[k2] += sc[n] * c[k2];
      }
      // S overwrites T row bl in LDS (t already consumed by this wave)
      short8 o;
#pragma unroll
      for (int k2 = 0; k2 < 8; ++k2) o[k2] = f2bf(s[k2] * inv);
      *(short8*)(R0 + bl * TSL + h * 128 + g * 8) = o;
    }
  }
  __syncthreads();

  // ===== Phase B stage 0: out_h = s_h @ Wv_h^T + bv -> ov (U, head-interleaved). Wave = head.
  {
    const int h2 = wid;
    short8 a[4];
#pragma unroll
    for (int ks = 0; ks < 4; ++ks)
      a[ks] = *(const short8*)(R0 + g * TSL + h2 * 128 + ks * 32 + q4 * 8);
#pragma unroll
    for (int nt = 0; nt < 2; ++nt) {
      f32x4 acc = {0.f, 0.f, 0.f, 0.f};
#pragma unroll
      for (int ks = 0; ks < 4; ++ks) {
        short8 bfr = *(const short8*)(wv + (h2 * 32 + nt * 16 + g) * 128 + ks * 32 + q4 * 8);
        acc = __builtin_amdgcn_mfma_f32_16x16x32_bf16(a[ks], bfr, acc, 0, 0, 0);
      }
      const int d = nt * 16 + g;
      const float bias = bv[h2 * 32 + d];
#pragma unroll
      for (int i = 0; i < 4; ++i)
        U[(q4 * 4 + i) * 136 + d * 4 + h2] = f2bf(acc[i] + bias);
    }
  }
  __syncthreads();

  // ===== Phase B stage 1: o1 = ov @ Wo^T + bo -> R0 (stride 136) + regs. Wave wid: nt = 2*wid+t2.
  f32x4 o1f[2];
  {
    short8 a1[4];
#pragma unroll
    for (int ks = 0; ks < 4; ++ks)
      a1[ks] = *(const short8*)(U + g * 136 + ks * 32 + q4 * 8);
#pragma unroll
    for (int t2 = 0; t2 < 2; ++t2) {
      const int nt = wid * 2 + t2;
      f32x4 acc = {0.f, 0.f, 0.f, 0.f};
#pragma unroll
      for (int ks = 0; ks < 4; ++ks) {
        short8 bfr = *(const short8*)(wo + (nt * 16 + g) * 128 + ks * 32 + q4 * 8);
        acc = __builtin_amdgcn_mfma_f32_16x16x32_bf16(a1[ks], bfr, acc, 0, 0, 0);
      }
      const float bias = bo[nt * 16 + g];
#pragma unroll
      for (int i = 0; i < 4; ++i) {
        acc[i] += bias;
        R0[(q4 * 4 + i) * 136 + nt * 16 + g] = f2bf(acc[i]);
      }
      o1f[t2] = acc;
    }
  }
  __syncthreads();

  // ===== Phase B stage 2: u = relu(o1 @ Wse1^T) -> U cols 0..31. Waves 0,1 only.
  if (wid < 2) {
    short8 a2[4];
#pragma unroll
    for (int ks = 0; ks < 4; ++ks)
      a2[ks] = *(const short8*)(R0 + g * 136 + ks * 32 + q4 * 8);
    const int nt = wid;
    f32x4 acc = {0.f, 0.f, 0.f, 0.f};
#pragma unroll
    for (int ks = 0; ks < 4; ++ks) {
      short8 bfr = *(const short8*)(ws1 + (nt * 16 + g) * 128 + ks * 32 + q4 * 8);
      acc = __builtin_amdgcn_mfma_f32_16x16x32_bf16(a2[ks], bfr, acc, 0, 0, 0);
    }
#pragma unroll
    for (int i = 0; i < 4; ++i)
      U[(q4 * 4 + i) * 136 + nt * 16 + g] = f2bf(fmaxf(acc[i], 0.f));
  }
  __syncthreads();

  // ===== Phase B stage 3: se_lin = u @ Wse2^T (K=32). Wave wid: nt = 2*wid+t2.
  f32x4 sef[2];
  {
    short8 a3 = *(const short8*)(U + g * 136 + q4 * 8);
#pragma unroll
    for (int t2 = 0; t2 < 2; ++t2) {
      const int nt = wid * 2 + t2;
      short8 bfr = *(const short8*)(ws2 + (nt * 16 + g) * 32 + q4 * 8);
      f32x4 z4 = {0.f, 0.f, 0.f, 0.f};
      sef[t2] = __builtin_amdgcn_mfma_f32_16x16x32_bf16(a3, bfr, z4, 0, 0, 0);
    }
  }

  // ===== Epilogue: SE gate, cross-wave residual-gate dot, final blend.
  const float L2E = 1.4426950408889634f;
  float o2v[2][4];
  float zc[4] = {0.f, 0.f, 0.f, 0.f};
#pragma unroll
  for (int t2 = 0; t2 < 2; ++t2) {
    const float w2 = wg[128 + (wid * 2 + t2) * 16 + g];
#pragma unroll
    for (int i = 0; i < 4; ++i) {
      const float se = 1.f / (1.f + exp2f(-sef[t2][i] * L2E));
      const float o2 = o1f[t2][i] * se;
      o2v[t2][i] = o2;
      zc[i] += w2 * o2;
    }
  }
#pragma unroll
  for (int i = 0; i < 4; ++i) {
    zc[i] += __shfl_xor(zc[i], 1);
    zc[i] += __shfl_xor(zc[i], 2);
    zc[i] += __shfl_xor(zc[i], 4);
    zc[i] += __shfl_xor(zc[i], 8);
  }
  if (g == 0) {
#pragma unroll
    for (int i = 0; i < 4; ++i) gz[wid][q4 * 4 + i] = zc[i];
  }
  __syncthreads();

  float wgx[8];
#pragma unroll
  for (int j = 0; j < 8; ++j) wgx[j] = wg[g * 8 + j];
  const float bgv = bg[0];
#pragma unroll
  for (int i = 0; i < 4; ++i) {
    const int row = r0 + q4 * 4 + i;
    const float* xp = x + (size_t)row * 128 + g * 8;
    float4 x0 = *(const float4*)xp;
    float4 x1 = *(const float4*)(xp + 4);
    float px = wgx[0]*x0.x + wgx[1]*x0.y + wgx[2]*x0.z + wgx[3]*x0.w
             + wgx[4]*x1.x + wgx[5]*x1.y + wgx[6]*x1.z + wgx[7]*x1.w;
    px += __shfl_xor(px, 1);
    px += __shfl_xor(px, 2);
    px += __shfl_xor(px, 4);
    px += __shfl_xor(px, 8);
    const int ri = q4 * 4 + i;
    const float z = px + gz[0][ri] + gz[1][ri] + gz[2][ri] + gz[3][ri] + bgv;
    const float gate = 1.f / (1.f + exp2f(-z * L2E));
#pragma unroll
    for (int t2 = 0; t2 < 2; ++t2) {
      const int col = (wid * 2 + t2) * 16 + g;
      const float xv = x[(size_t)row * 128 + col];
      out[(size_t)row * 128 + col] = xv + gate * (o2v[t2][i] - xv);
    }
  }
}

// ---------------------------------------------------------------------------
extern "C" void kernel_launch(void* const* d_in, const int* in_sizes, int n_in,
                              void* d_out, int out_size, void* d_ws, size_t ws_size,
                              hipStream_t stream)
{
  const float* x   = (const float*)d_in[0];
  const float* nb  = (const float*)d_in[1];
  const float* Wq  = (const float*)d_in[2];
  const float* bq  = (const float*)d_in[3];
  const float* Wk  = (const float*)d_in[4];
  // d_in[5] = bk: dropped (softmax shift-invariance)
  const float* Wv  = (const float*)d_in[6];
  const float* bv  = (const float*)d_in[7];
  const float* Wo  = (const float*)d_in[8];
  const float* bo  = (const float*)d_in[9];
  const float* Ws1 = (const float*)d_in[10];
  const float* Ws2 = (const float*)d_in[11];
  const float* wg  = (const float*)d_in[12];
  const float* bg  = (const float*)d_in[13];
  float* out = (float*)d_out;

  // Workspace: bf16 weights only (~144 KB). No TS intermediate anymore.
  short* wqb  = (short*)d_ws;
  short* wktb = wqb  + 16384;
  short* wvb  = wktb + 16384;
  short* wob  = wvb  + 16384;
  short* ws1b = wob  + 16384;
  short* ws2b = ws1b + 4096;

  k_prep <<<64, 256, 0, stream>>>(Wq, Wk, Wv, Wo, Ws1, Ws2,
                                  wqb, wktb, wvb, wob, ws1b, ws2b);
  k_fused<<<4096, 256, 0, stream>>>(x, nb, bq, wqb, wktb, wvb, wob, ws1b, ws2b,
                                    bv, bo, wg, bg, out);
}